// Round 1
// 139.984 us; speedup vs baseline: 1.0112x; 1.0112x over previous
//
#include <hip/hip_runtime.h>
#include <math.h>

#define BB 4
#define CC 256
#define HWN 4096
#define NTOK 16384                 // BB*HWN
#define SCQ 0.09016844136f         // (1/sqrt(256)) * log2(e)

typedef __attribute__((ext_vector_type(8))) short short8;
typedef __attribute__((ext_vector_type(4))) float f32x4;
typedef __attribute__((ext_vector_type(2))) float f32x2;
typedef unsigned short ushort_t;

__device__ __forceinline__ ushort_t f2bf(float f) {
    unsigned int u = __float_as_uint(f);
    unsigned int r = (u + 0x7FFFu + ((u >> 16) & 1u)) >> 16;   // RNE
    return (ushort_t)r;
}
__device__ __forceinline__ unsigned int pack2(float a, float b) {
    return (unsigned int)f2bf(a) | ((unsigned int)f2bf(b) << 16);
}

// ---------------------------------------------------------------------------
// Kernel 0: one-time weight prep. Converts q_w (pre-scaled by SCQ) and k_w
// to bf16 in workspace so proj blocks stop re-converting 512 KB of fp32
// weights each. Also zeroes den/nx/ny (16384 threads x 3 stores = 49152).
// ---------------------------------------------------------------------------
__global__ __launch_bounds__(256) void wprep_kernel(
    const float* __restrict__ q_w, const float* __restrict__ k_w,
    ushort_t* __restrict__ qwb, ushort_t* __restrict__ kwb,
    float* __restrict__ zbuf)
{
    int t = blockIdx.x * 256 + threadIdx.x;          // grid 64 -> 16384 threads
    float4 q4 = *(const float4*)&q_w[(size_t)t * 4];
    float4 k4 = *(const float4*)&k_w[(size_t)t * 4];
    unsigned long long qo = (unsigned long long)pack2(q4.x * SCQ, q4.y * SCQ)
                          | ((unsigned long long)pack2(q4.z * SCQ, q4.w * SCQ) << 32);
    unsigned long long ko = (unsigned long long)pack2(k4.x, k4.y)
                          | ((unsigned long long)pack2(k4.z, k4.w) << 32);
    *(unsigned long long*)&qwb[(size_t)t * 4] = qo;
    *(unsigned long long*)&kwb[(size_t)t * 4] = ko;
    zbuf[t] = 0.f; zbuf[t + NTOK] = 0.f; zbuf[t + 2 * NTOK] = 0.f;
}

// ---------------------------------------------------------------------------
// Fused projection. Block = 64 tokens x 128 d-half (d split across twin
// blocks i and i+256 -> same XCD -> feature reads L2-shared, 2 blocks/CU so
// 2 waves/SIMD for latency hiding). Phase 1: stage feature [256c x 64tok]
// fp32 -> bf16 LDS token-major. Phase 2 (no barriers): per wave, 32 d x
// 256 c MFMA for Q and K, weights loaded pre-converted bf16 (short8).
// ---------------------------------------------------------------------------
__global__ __launch_bounds__(256, 2) void proj_kernel(
    const float* __restrict__ feature,
    const ushort_t* __restrict__ qwb, const ushort_t* __restrict__ kwb,
    const float* __restrict__ q_bias, const float* __restrict__ k_bias,
    ushort_t* __restrict__ qb, ushort_t* __restrict__ kb)
{
    int id = blockIdx.x;
    int dh = id >> 8;            // 0..1: twin blocks 256 apart share (b,tt)
    id &= 255;
    int tt = id & 63;
    int b  = id >> 6;
    int tok0 = tt * 64;

    int t = threadIdx.x, w = t >> 6, lane = t & 63;
    int n16 = lane & 15, quad = lane >> 4;

    __shared__ float    lsA[64][69];    // [c-in-chunk][tok] fp32, stride 69
    __shared__ ushort_t lsB[64][264];   // [tok][c 0..255] bf16, stride 264

    const float* F = feature + (size_t)(b * CC) * HWN;

    int cl = t >> 2, tg = (t & 3) * 16;
    int tokw = t >> 2, c16 = (t & 3) * 16;

    for (int ch = 0; ch < 4; ch++) {
        const float* src = F + (size_t)(ch * 64 + cl) * HWN + tok0 + tg;
        *(float4*)&lsA[cl][tg]      = *(const float4*)(src);
        *(float4*)&lsA[cl][tg + 4]  = *(const float4*)(src + 4);
        *(float4*)&lsA[cl][tg + 8]  = *(const float4*)(src + 8);
        *(float4*)&lsA[cl][tg + 12] = *(const float4*)(src + 12);
        __syncthreads();
        #pragma unroll
        for (int jj = 0; jj < 8; jj++)
            *(unsigned int*)&lsB[tokw][ch * 64 + c16 + 2 * jj] =
                pack2(lsA[c16 + 2 * jj][tokw], lsA[c16 + 2 * jj + 1][tokw]);
        __syncthreads();
    }

    int dw0 = dh * 128 + w * 32;
    #pragma unroll
    for (int dsub = 0; dsub < 2; dsub++) {
        int d0 = dw0 + dsub * 16;
        f32x4 accq[4], acck[4];
        #pragma unroll
        for (int i = 0; i < 4; i++) {
            accq[i] = (f32x4){0.f, 0.f, 0.f, 0.f};
            acck[i] = (f32x4){0.f, 0.f, 0.f, 0.f};
        }
        #pragma unroll
        for (int kc = 0; kc < 8; kc++) {
            size_t off = (size_t)(d0 + n16) * CC + kc * 32 + quad * 8;
            short8 aq = *(const short8*)&qwb[off];
            short8 ak = *(const short8*)&kwb[off];
            #pragma unroll
            for (int tokt = 0; tokt < 4; tokt++) {
                short8 bf = *(const short8*)&lsB[tokt * 16 + n16][kc * 32 + quad * 8];
                accq[tokt] = __builtin_amdgcn_mfma_f32_16x16x32_bf16(aq, bf, accq[tokt], 0, 0, 0);
                acck[tokt] = __builtin_amdgcn_mfma_f32_16x16x32_bf16(ak, bf, acck[tokt], 0, 0, 0);
            }
        }
        float bqv[4], bkv[4];
        #pragma unroll
        for (int r = 0; r < 4; r++) {
            bqv[r] = q_bias[d0 + quad * 4 + r] * SCQ;
            bkv[r] = k_bias[d0 + quad * 4 + r];
        }
        #pragma unroll
        for (int tokt = 0; tokt < 4; tokt++) {
            size_t row = (size_t)(b * HWN + tok0 + tokt * 16 + n16) * CC + d0 + quad * 4;
            ushort4 oq, ok;
            oq.x = f2bf(accq[tokt][0] + bqv[0]); oq.y = f2bf(accq[tokt][1] + bqv[1]);
            oq.z = f2bf(accq[tokt][2] + bqv[2]); oq.w = f2bf(accq[tokt][3] + bqv[3]);
            ok.x = f2bf(acck[tokt][0] + bkv[0]); ok.y = f2bf(acck[tokt][1] + bkv[1]);
            ok.z = f2bf(acck[tokt][2] + bkv[2]); ok.w = f2bf(acck[tokt][3] + bkv[3]);
            *(ushort4*)&qb[row] = oq;
            *(ushort4*)&kb[row] = ok;
        }
    }
}

// ---------------------------------------------------------------------------
// Flash MFMA attention. Block = (b, 256-q, 512-key range), 4 waves; each wave
// owns 64 q-rows. Grid 512 with bijective XCD swizzle (512 = 8*64 exact) so
// the 16 qt-blocks sharing a K-range colocate on one XCD's L2.
// 32-key stages, double-buffered 2 x 16 KB XOR-swizzled LDS.
// den/nx/ny accumulated as float2 pairs via elementwise fma so the backend
// can emit v_pk_{add,fma}_f32 (halves the softmax-accum VALU instrs).
// ---------------------------------------------------------------------------
__global__ __launch_bounds__(256, 2) void attn_kernel(
    const ushort_t* __restrict__ qb, const ushort_t* __restrict__ kb,
    const float* __restrict__ flow,
    float* __restrict__ den_g, float* __restrict__ nx_g, float* __restrict__ ny_g)
{
    int id = (blockIdx.x & 7) * 64 + (blockIdx.x >> 3);   // XCD-aware swizzle
    int qt = id & 15; id >>= 4;
    int sr = id & 7;  id >>= 3;
    int b = id;

    int t = threadIdx.x;
    int w = t >> 6, lane = t & 63;
    int n16 = lane & 15, quad = lane >> 4;

    int q0 = qt * 256 + w * 64;
    int s_beg = sr * 512;

    const ushort_t* Qb = qb + (size_t)b * HWN * CC;
    const ushort_t* Kb = kb + (size_t)b * HWN * CC;

    __shared__ __align__(16) ushort_t lk[2][8192];   // 2 x 16 KB swizzled K
    __shared__ float lflow[1024];                     // 512 vx + 512 vy

    const float* fx = flow + (size_t)b * 2 * HWN;
    const float* fy = fx + HWN;
    lflow[t]        = fx[s_beg + t];
    lflow[t + 256]  = fx[s_beg + t + 256];
    lflow[t + 512]  = fy[s_beg + t];
    lflow[t + 768]  = fy[s_beg + t + 256];

    short8 qf[4][8];
    #pragma unroll
    for (int tq = 0; tq < 4; tq++)
        #pragma unroll
        for (int c = 0; c < 8; c++)
            qf[tq][c] = *(const short8*)&Qb[(size_t)(q0 + tq * 16 + n16) * CC
                                            + c * 32 + quad * 8];

    // staging source offsets (XOR swizzle on 16B granules), loop-invariant
    int srcoff[4];
    #pragma unroll
    for (int i = 0; i < 4; i++) {
        int G = i * 256 + t;
        int r = G >> 5, j = G & 31;        // 32 rows x 32 granules
        srcoff[i] = (r * 32 + (j ^ r)) * 16;
    }
    int p16[8];
    #pragma unroll
    for (int c = 0; c < 8; c++)
        p16[c] = (((c * 4 + quad) ^ n16) & 31) * 16;

    f32x2 den[4][2], nxa[4][2], nya[4][2];
    #pragma unroll
    for (int tq = 0; tq < 4; tq++)
        #pragma unroll
        for (int j = 0; j < 2; j++) {
            den[tq][j] = (f32x2){0.f, 0.f};
            nxa[tq][j] = (f32x2){0.f, 0.f};
            nya[tq][j] = (f32x2){0.f, 0.f};
        }

    // prologue: stage tile 0 into buffer 0
    {
        const char* gsrc = (const char*)(Kb + (size_t)s_beg * CC);
        char* ldst = (char*)lk[0] + t * 16;
        #pragma unroll
        for (int i = 0; i < 4; i++)
            __builtin_amdgcn_global_load_lds(
                (const __attribute__((address_space(1))) unsigned int*)(gsrc + srcoff[i]),
                (__attribute__((address_space(3))) unsigned int*)(ldst + i * 4096),
                16, 0, 0);
    }

    for (int st = 0; st < 16; st++) {
        __syncthreads();   // buffer st&1 staged; prior reads of other buffer done
        if (st + 1 < 16) {
            const char* gsrc = (const char*)(Kb + (size_t)(s_beg + (st + 1) * 32) * CC);
            char* ldst = (char*)lk[(st + 1) & 1] + t * 16;
            #pragma unroll
            for (int i = 0; i < 4; i++)
                __builtin_amdgcn_global_load_lds(
                    (const __attribute__((address_space(1))) unsigned int*)(gsrc + srcoff[i]),
                    (__attribute__((address_space(3))) unsigned int*)(ldst + i * 4096),
                    16, 0, 0);
        }
        const char* base = (const char*)lk[st & 1];

        #pragma unroll
        for (int bt = 0; bt < 2; bt++) {
            int rbase = (bt * 16 + n16) * 512;
            int x16   = bt ? 256 : 0;
            f32x4 a0 = {0.f, 0.f, 0.f, 0.f};
            f32x4 a1 = {0.f, 0.f, 0.f, 0.f};
            f32x4 a2 = {0.f, 0.f, 0.f, 0.f};
            f32x4 a3 = {0.f, 0.f, 0.f, 0.f};
            #pragma unroll
            for (int c = 0; c < 8; c++) {
                short8 kf = *(const short8*)(base + rbase + (p16[c] ^ x16));
                a0 = __builtin_amdgcn_mfma_f32_16x16x32_bf16(qf[0][c], kf, a0, 0, 0, 0);
                a1 = __builtin_amdgcn_mfma_f32_16x16x32_bf16(qf[1][c], kf, a1, 0, 0, 0);
                a2 = __builtin_amdgcn_mfma_f32_16x16x32_bf16(qf[2][c], kf, a2, 0, 0, 0);
                a3 = __builtin_amdgcn_mfma_f32_16x16x32_bf16(qf[3][c], kf, a3, 0, 0, 0);
            }
            int sidx = st * 32 + bt * 16 + n16;
            float vx = lflow[sidx];
            float vy = lflow[512 + sidx];
            f32x2 vx2 = (f32x2){vx, vx};
            f32x2 vy2 = (f32x2){vy, vy};
            #pragma unroll
            for (int tq = 0; tq < 4; tq++) {
                f32x4 a = (tq == 0) ? a0 : (tq == 1) ? a1 : (tq == 2) ? a2 : a3;
                f32x2 p0 = (f32x2){exp2f(a[0]), exp2f(a[1])};
                f32x2 p1 = (f32x2){exp2f(a[2]), exp2f(a[3])};
                den[tq][0] += p0;
                den[tq][1] += p1;
                nxa[tq][0] = __builtin_elementwise_fma(p0, vx2, nxa[tq][0]);
                nxa[tq][1] = __builtin_elementwise_fma(p1, vx2, nxa[tq][1]);
                nya[tq][0] = __builtin_elementwise_fma(p0, vy2, nya[tq][0]);
                nya[tq][1] = __builtin_elementwise_fma(p1, vy2, nya[tq][1]);
            }
        }
    }

    #pragma unroll
    for (int tq = 0; tq < 4; tq++)
        #pragma unroll
        for (int j = 0; j < 2; j++)
            #pragma unroll
            for (int e = 0; e < 2; e++) {
                float dv = den[tq][j][e];
                float xv = nxa[tq][j][e];
                float yv = nya[tq][j][e];
                #pragma unroll
                for (int off = 8; off >= 1; off >>= 1) {
                    dv += __shfl_down(dv, off, 16);
                    xv += __shfl_down(xv, off, 16);
                    yv += __shfl_down(yv, off, 16);
                }
                if (n16 == 0) {
                    int r = j * 2 + e;
                    int qrow = q0 + tq * 16 + quad * 4 + r;
                    int gi = b * HWN + qrow;
                    atomicAdd(&den_g[gi], dv);
                    atomicAdd(&nx_g[gi],  xv);
                    atomicAdd(&ny_g[gi],  yv);
                }
            }
}

// ---------------------------------------------------------------------------
__global__ __launch_bounds__(256) void finalize_kernel(
    const float* __restrict__ den_g, const float* __restrict__ nx_g,
    const float* __restrict__ ny_g, float* __restrict__ out)
{
    int idx = blockIdx.x * 256 + threadIdx.x;  // b*HW + n
    int b = idx >> 12, n = idx & 4095;
    float inv = 1.0f / den_g[idx];
    out[(size_t)b * 2 * HWN + n]       = nx_g[idx] * inv;
    out[(size_t)b * 2 * HWN + HWN + n] = ny_g[idx] * inv;
}

extern "C" void kernel_launch(void* const* d_in, const int* in_sizes, int n_in,
                              void* d_out, int out_size, void* d_ws, size_t ws_size,
                              hipStream_t stream) {
    const float* feature = (const float*)d_in[0];
    const float* flow    = (const float*)d_in[1];
    const float* q_w     = (const float*)d_in[2];
    const float* q_b     = (const float*)d_in[3];
    const float* k_w     = (const float*)d_in[4];
    const float* k_b     = (const float*)d_in[5];
    float* out = (float*)d_out;

    ushort_t* qbuf = (ushort_t*)d_ws;                     // [NTOK][CC] bf16
    ushort_t* kbuf = qbuf + (size_t)NTOK * CC;            // [NTOK][CC] bf16
    float* den = (float*)(kbuf + (size_t)NTOK * CC);      // [NTOK]
    float* nx  = den + NTOK;
    float* ny  = nx + NTOK;
    ushort_t* qwb = (ushort_t*)(ny + NTOK);               // [CC][CC] bf16 (pre-scaled)
    ushort_t* kwb = qwb + (size_t)CC * CC;                // [CC][CC] bf16

    wprep_kernel<<<64, 256, 0, stream>>>(q_w, k_w, qwb, kwb, den); // + zero den/nx/ny
    proj_kernel<<<512, 256, 0, stream>>>(feature, qwb, kwb, q_b, k_b, qbuf, kbuf);
    attn_kernel<<<512, 256, 0, stream>>>(qbuf, kbuf, flow, den, nx, ny);
    finalize_kernel<<<64, 256, 0, stream>>>(den, nx, ny, out);
}